// Round 1
// baseline (186.437 us; speedup 1.0000x reference)
//
#include <hip/hip_runtime.h>

#define TP_ 4
#define TOKENS_ 8192
#define HIDDEN_ 4096
#define EPS_ 1e-6f
#define FP8MAX_ 448.0f

static constexpr size_t NELEM = (size_t)TOKENS_ * HIDDEN_;  // 33,554,432

// Pass 1: all-reduce over TP shards + RMSNorm, one block per row (256 thr,
// 16 floats/thread via 4x float4). Writes fp32 normed into d_out[0..N),
// accumulates global amax into d_ws via uint-bitpattern atomicMax.
__global__ __launch_bounds__(256) void k_fused_norm(
    const float* __restrict__ hs, const float* __restrict__ w,
    float* __restrict__ normed, unsigned int* __restrict__ amax_bits)
{
    const int row = blockIdx.x;
    const int tid = threadIdx.x;
    const size_t S4 = NELEM / 4;  // shard stride in float4 units
    const float4* __restrict__ base =
        reinterpret_cast<const float4*>(hs) + (size_t)row * (HIDDEN_ / 4);
    const float4* __restrict__ w4 = reinterpret_cast<const float4*>(w);

    float4 sv[4];
    float ss = 0.f;
#pragma unroll
    for (int j = 0; j < 4; ++j) {
        const size_t idx = (size_t)tid + j * 256;
        float4 a = base[idx];
        float4 b = base[idx + S4];
        float4 c = base[idx + 2 * S4];
        float4 d = base[idx + 3 * S4];
        float4 s;
        s.x = (a.x + b.x) + (c.x + d.x);
        s.y = (a.y + b.y) + (c.y + d.y);
        s.z = (a.z + b.z) + (c.z + d.z);
        s.w = (a.w + b.w) + (c.w + d.w);
        sv[j] = s;
        ss += s.x * s.x + s.y * s.y + s.z * s.z + s.w * s.w;
    }

    // block-reduce sum of squares (wave64 shuffle + LDS across 4 waves)
    __shared__ float red[4];
#pragma unroll
    for (int off = 32; off > 0; off >>= 1) ss += __shfl_down(ss, off, 64);
    const int wave = tid >> 6;
    if ((tid & 63) == 0) red[wave] = ss;
    __syncthreads();
    ss = red[0] + red[1] + red[2] + red[3];
    const float inv = rsqrtf(ss * (1.0f / HIDDEN_) + EPS_);

    float4* __restrict__ out =
        reinterpret_cast<float4*>(normed) + (size_t)row * (HIDDEN_ / 4);
    float am = 0.f;
#pragma unroll
    for (int j = 0; j < 4; ++j) {
        const size_t idx = (size_t)tid + j * 256;
        float4 wv = w4[idx];
        float4 s = sv[j];
        float4 o;
        o.x = s.x * inv * wv.x;
        o.y = s.y * inv * wv.y;
        o.z = s.z * inv * wv.z;
        o.w = s.w * inv * wv.w;
        out[idx] = o;
        am = fmaxf(am, fmaxf(fmaxf(fabsf(o.x), fabsf(o.y)),
                             fmaxf(fabsf(o.z), fabsf(o.w))));
    }

    // block-reduce max, one atomic per block
    __shared__ float redm[4];
#pragma unroll
    for (int off = 32; off > 0; off >>= 1)
        am = fmaxf(am, __shfl_down(am, off, 64));
    if ((tid & 63) == 0) redm[wave] = am;
    __syncthreads();
    if (tid == 0) {
        am = fmaxf(fmaxf(redm[0], redm[1]), fmaxf(redm[2], redm[3]));
        atomicMax(amax_bits, __float_as_uint(am));  // all values >= 0: uint order == float order
    }
}

// Pass 2: read global amax -> scale, clip in place, write scale scalar.
__global__ __launch_bounds__(256) void k_quant(
    float* __restrict__ data, const unsigned int* __restrict__ amax_bits,
    float* __restrict__ scale_out)
{
    const float amax = __uint_as_float(*amax_bits);
    const float scale = fmaxf(amax, 1e-12f) / FP8MAX_;
    const float invs = 1.0f / scale;
    const size_t n4 = NELEM / 4;
    float4* __restrict__ d4 = reinterpret_cast<float4*>(data);
    const size_t stride = (size_t)gridDim.x * blockDim.x;
    for (size_t i = (size_t)blockIdx.x * blockDim.x + threadIdx.x; i < n4;
         i += stride) {
        float4 v = d4[i];
        v.x = fminf(fmaxf(v.x * invs, -FP8MAX_), FP8MAX_);
        v.y = fminf(fmaxf(v.y * invs, -FP8MAX_), FP8MAX_);
        v.z = fminf(fmaxf(v.z * invs, -FP8MAX_), FP8MAX_);
        v.w = fminf(fmaxf(v.w * invs, -FP8MAX_), FP8MAX_);
        d4[i] = v;
    }
    if (blockIdx.x == 0 && threadIdx.x == 0) scale_out[0] = scale;
}

extern "C" void kernel_launch(void* const* d_in, const int* in_sizes, int n_in,
                              void* d_out, int out_size, void* d_ws, size_t ws_size,
                              hipStream_t stream) {
    const float* hs = (const float*)d_in[0];   // [TP, TOKENS, HIDDEN]
    // d_in[1] = residual: unused by the reference computation
    const float* w  = (const float*)d_in[2];   // [HIDDEN]
    float* out = (float*)d_out;                // [N] q values + [1] scale
    unsigned int* amax_bits = (unsigned int*)d_ws;

    hipMemsetAsync(d_ws, 0, sizeof(unsigned int), stream);
    k_fused_norm<<<TOKENS_, 256, 0, stream>>>(hs, w, out, amax_bits);
    k_quant<<<2048, 256, 0, stream>>>(out, amax_bits, out + NELEM);
}

// Round 2
// 181.186 us; speedup vs baseline: 1.0290x; 1.0290x over previous
//
#include <hip/hip_runtime.h>
#include <hip/hip_fp16.h>

#define TP_ 4
#define TOKENS_ 8192
#define HIDDEN_ 4096
#define EPS_ 1e-6f
#define FP8MAX_ 448.0f

static constexpr size_t NELEM = (size_t)TOKENS_ * HIDDEN_;  // 33,554,432
static constexpr size_t WS_AMAX_BYTES = 16;                 // amax at ws+0, fp16 buf at ws+16
static constexpr size_t WS_NEEDED = WS_AMAX_BYTES + NELEM * sizeof(unsigned short);

static __device__ inline unsigned int pack_half2(float a, float b) {
    __half2 h = __floats2half2_rn(a, b);
    return *reinterpret_cast<unsigned int*>(&h);
}

// ---------------- fp16-intermediate path ----------------

// Pass 1: all-reduce + RMSNorm, one block per row. Writes fp16 normed into
// d_ws (+16), accumulates global amax (uint bitpattern) at d_ws[0].
__global__ __launch_bounds__(256) void k_norm_h(
    const float* __restrict__ hs, const float* __restrict__ w,
    unsigned int* __restrict__ normed_h2,  // NELEM/2 uints (half2)
    unsigned int* __restrict__ amax_bits)
{
    const int row = blockIdx.x;
    const int tid = threadIdx.x;
    const size_t S4 = NELEM / 4;  // shard stride in float4 units
    const float4* __restrict__ base =
        reinterpret_cast<const float4*>(hs) + (size_t)row * (HIDDEN_ / 4);
    const float4* __restrict__ w4 = reinterpret_cast<const float4*>(w);

    float4 sv[4];
    float ss = 0.f;
#pragma unroll
    for (int j = 0; j < 4; ++j) {
        const size_t idx = (size_t)tid + j * 256;
        float4 a = base[idx];
        float4 b = base[idx + S4];
        float4 c = base[idx + 2 * S4];
        float4 d = base[idx + 3 * S4];
        float4 s;
        s.x = (a.x + b.x) + (c.x + d.x);
        s.y = (a.y + b.y) + (c.y + d.y);
        s.z = (a.z + b.z) + (c.z + d.z);
        s.w = (a.w + b.w) + (c.w + d.w);
        sv[j] = s;
        ss += s.x * s.x + s.y * s.y + s.z * s.z + s.w * s.w;
    }

    __shared__ float red[4];
#pragma unroll
    for (int off = 32; off > 0; off >>= 1) ss += __shfl_down(ss, off, 64);
    const int wave = tid >> 6;
    if ((tid & 63) == 0) red[wave] = ss;
    __syncthreads();
    ss = red[0] + red[1] + red[2] + red[3];
    const float inv = rsqrtf(ss * (1.0f / HIDDEN_) + EPS_);

    uint2* __restrict__ out =  // 4 halves per uint2, row stride HIDDEN/4 uint2
        reinterpret_cast<uint2*>(normed_h2) + (size_t)row * (HIDDEN_ / 4);
    float am = 0.f;
#pragma unroll
    for (int j = 0; j < 4; ++j) {
        const size_t idx = (size_t)tid + j * 256;
        float4 wv = w4[idx];
        float4 s = sv[j];
        float4 o;
        o.x = s.x * inv * wv.x;
        o.y = s.y * inv * wv.y;
        o.z = s.z * inv * wv.z;
        o.w = s.w * inv * wv.w;
        uint2 p;
        p.x = pack_half2(o.x, o.y);
        p.y = pack_half2(o.z, o.w);
        out[idx] = p;
        am = fmaxf(am, fmaxf(fmaxf(fabsf(o.x), fabsf(o.y)),
                             fmaxf(fabsf(o.z), fabsf(o.w))));
    }

    __shared__ float redm[4];
#pragma unroll
    for (int off = 32; off > 0; off >>= 1)
        am = fmaxf(am, __shfl_down(am, off, 64));
    if ((tid & 63) == 0) redm[wave] = am;
    __syncthreads();
    if (tid == 0) {
        am = fmaxf(fmaxf(redm[0], redm[1]), fmaxf(redm[2], redm[3]));
        atomicMax(amax_bits, __float_as_uint(am));  // values >= 0
    }
}

// Pass 2: read fp16 normed (16B = 8 halves / thread-iter), scale+clip,
// write fp32 q. Also writes the scale scalar.
__global__ __launch_bounds__(256) void k_quant_h(
    const unsigned int* __restrict__ normed_h2,
    const unsigned int* __restrict__ amax_bits,
    float* __restrict__ q_out, float* __restrict__ scale_out)
{
    const float amax = __uint_as_float(*amax_bits);
    const float scale = fmaxf(amax, 1e-12f) / FP8MAX_;
    const float invs = 1.0f / scale;
    const size_t n8 = NELEM / 8;
    const uint4* __restrict__ src = reinterpret_cast<const uint4*>(normed_h2);
    float4* __restrict__ dst = reinterpret_cast<float4*>(q_out);
    const size_t stride = (size_t)gridDim.x * blockDim.x;
    for (size_t i = (size_t)blockIdx.x * blockDim.x + threadIdx.x; i < n8;
         i += stride) {
        uint4 u = src[i];
        float2 f0 = __half22float2(*reinterpret_cast<const __half2*>(&u.x));
        float2 f1 = __half22float2(*reinterpret_cast<const __half2*>(&u.y));
        float2 f2 = __half22float2(*reinterpret_cast<const __half2*>(&u.z));
        float2 f3 = __half22float2(*reinterpret_cast<const __half2*>(&u.w));
        float4 a, b;
        a.x = fminf(fmaxf(f0.x * invs, -FP8MAX_), FP8MAX_);
        a.y = fminf(fmaxf(f0.y * invs, -FP8MAX_), FP8MAX_);
        a.z = fminf(fmaxf(f1.x * invs, -FP8MAX_), FP8MAX_);
        a.w = fminf(fmaxf(f1.y * invs, -FP8MAX_), FP8MAX_);
        b.x = fminf(fmaxf(f2.x * invs, -FP8MAX_), FP8MAX_);
        b.y = fminf(fmaxf(f2.y * invs, -FP8MAX_), FP8MAX_);
        b.z = fminf(fmaxf(f3.x * invs, -FP8MAX_), FP8MAX_);
        b.w = fminf(fmaxf(f3.y * invs, -FP8MAX_), FP8MAX_);
        dst[i * 2] = a;
        dst[i * 2 + 1] = b;
    }
    if (blockIdx.x == 0 && threadIdx.x == 0) scale_out[0] = scale;
}

// ---------------- fallback fp32-in-d_out path (proven, round 1) ----------------

__global__ __launch_bounds__(256) void k_fused_norm(
    const float* __restrict__ hs, const float* __restrict__ w,
    float* __restrict__ normed, unsigned int* __restrict__ amax_bits)
{
    const int row = blockIdx.x;
    const int tid = threadIdx.x;
    const size_t S4 = NELEM / 4;
    const float4* __restrict__ base =
        reinterpret_cast<const float4*>(hs) + (size_t)row * (HIDDEN_ / 4);
    const float4* __restrict__ w4 = reinterpret_cast<const float4*>(w);

    float4 sv[4];
    float ss = 0.f;
#pragma unroll
    for (int j = 0; j < 4; ++j) {
        const size_t idx = (size_t)tid + j * 256;
        float4 a = base[idx];
        float4 b = base[idx + S4];
        float4 c = base[idx + 2 * S4];
        float4 d = base[idx + 3 * S4];
        float4 s;
        s.x = (a.x + b.x) + (c.x + d.x);
        s.y = (a.y + b.y) + (c.y + d.y);
        s.z = (a.z + b.z) + (c.z + d.z);
        s.w = (a.w + b.w) + (c.w + d.w);
        sv[j] = s;
        ss += s.x * s.x + s.y * s.y + s.z * s.z + s.w * s.w;
    }
    __shared__ float red[4];
#pragma unroll
    for (int off = 32; off > 0; off >>= 1) ss += __shfl_down(ss, off, 64);
    const int wave = tid >> 6;
    if ((tid & 63) == 0) red[wave] = ss;
    __syncthreads();
    ss = red[0] + red[1] + red[2] + red[3];
    const float inv = rsqrtf(ss * (1.0f / HIDDEN_) + EPS_);

    float4* __restrict__ out =
        reinterpret_cast<float4*>(normed) + (size_t)row * (HIDDEN_ / 4);
    float am = 0.f;
#pragma unroll
    for (int j = 0; j < 4; ++j) {
        const size_t idx = (size_t)tid + j * 256;
        float4 wv = w4[idx];
        float4 s = sv[j];
        float4 o;
        o.x = s.x * inv * wv.x;
        o.y = s.y * inv * wv.y;
        o.z = s.z * inv * wv.z;
        o.w = s.w * inv * wv.w;
        out[idx] = o;
        am = fmaxf(am, fmaxf(fmaxf(fabsf(o.x), fabsf(o.y)),
                             fmaxf(fabsf(o.z), fabsf(o.w))));
    }
    __shared__ float redm[4];
#pragma unroll
    for (int off = 32; off > 0; off >>= 1)
        am = fmaxf(am, __shfl_down(am, off, 64));
    if ((tid & 63) == 0) redm[wave] = am;
    __syncthreads();
    if (tid == 0) {
        am = fmaxf(fmaxf(redm[0], redm[1]), fmaxf(redm[2], redm[3]));
        atomicMax(amax_bits, __float_as_uint(am));
    }
}

__global__ __launch_bounds__(256) void k_quant(
    float* __restrict__ data, const unsigned int* __restrict__ amax_bits,
    float* __restrict__ scale_out)
{
    const float amax = __uint_as_float(*amax_bits);
    const float scale = fmaxf(amax, 1e-12f) / FP8MAX_;
    const float invs = 1.0f / scale;
    const size_t n4 = NELEM / 4;
    float4* __restrict__ d4 = reinterpret_cast<float4*>(data);
    const size_t stride = (size_t)gridDim.x * blockDim.x;
    for (size_t i = (size_t)blockIdx.x * blockDim.x + threadIdx.x; i < n4;
         i += stride) {
        float4 v = d4[i];
        v.x = fminf(fmaxf(v.x * invs, -FP8MAX_), FP8MAX_);
        v.y = fminf(fmaxf(v.y * invs, -FP8MAX_), FP8MAX_);
        v.z = fminf(fmaxf(v.z * invs, -FP8MAX_), FP8MAX_);
        v.w = fminf(fmaxf(v.w * invs, -FP8MAX_), FP8MAX_);
        d4[i] = v;
    }
    if (blockIdx.x == 0 && threadIdx.x == 0) scale_out[0] = scale;
}

extern "C" void kernel_launch(void* const* d_in, const int* in_sizes, int n_in,
                              void* d_out, int out_size, void* d_ws, size_t ws_size,
                              hipStream_t stream) {
    const float* hs = (const float*)d_in[0];   // [TP, TOKENS, HIDDEN]
    // d_in[1] = residual: unused by the reference computation
    const float* w  = (const float*)d_in[2];   // [HIDDEN]
    float* out = (float*)d_out;                // [N] q values + [1] scale
    unsigned int* amax_bits = (unsigned int*)d_ws;

    hipMemsetAsync(d_ws, 0, sizeof(unsigned int), stream);
    if (ws_size >= WS_NEEDED) {
        unsigned int* normed_h2 =
            (unsigned int*)((char*)d_ws + WS_AMAX_BYTES);
        k_norm_h<<<TOKENS_, 256, 0, stream>>>(hs, w, normed_h2, amax_bits);
        k_quant_h<<<2048, 256, 0, stream>>>(normed_h2, amax_bits, out,
                                            out + NELEM);
    } else {
        k_fused_norm<<<TOKENS_, 256, 0, stream>>>(hs, w, out, amax_bits);
        k_quant<<<2048, 256, 0, stream>>>(out, amax_bits, out + NELEM);
    }
}